// Round 1
// 71.343 us; speedup vs baseline: 1.0378x; 1.0378x over previous
//
#include <hip/hip_runtime.h>
#include <stdint.h>

// MulticlassDice — N=8 samples, C=8 classes, 512x512 px, int32 labels 0..7.
// Whole computation = 192 histogram counters (count_in, count_tg, inter per
// (n,c)) + tiny epilogue. 16 MiB stream -> ~2.7 us HBM floor.
//
// R6 = R2 structure (2 plain graph nodes, no atomics, best measured 74.0 us)
// with the partial array halved: BLKS 64 -> 32. dice_count keeps identical
// byte traffic (32 px/thread, 256 blocks = 1/CU, ~64 KB loads in flight/CU
// >> 9 KB BW*latency product), while dice_final's latency-bound strided
// reduction halves (48 -> 24 KB, 64 -> 32 serial loads/thread).
// SWAR note: 32 px/thread means 8-bit class fields only survive butterfly
// rounds 1-2 (max 32*4=128 <= 255); split to 16-bit before round 3
// (max 32*64=2048 <= 65535).
// Measured loop remains dominated by the harness's 268 MB ws re-poison
// (~44 us @ ~77% HBM peak) + reset()'s tiny dispatches — outside kernel
// control. This targets the only remaining controllable slice.

#define NCLS    8
#define NSAMP   8
#define PIX     (512 * 512)
#define BLKS    32            // blocks per sample
#define SMOOTHF 1e-5f

typedef unsigned long long u64;
typedef unsigned int u32;

// ws layout: u32 partial[NSAMP*BLKS][24]
//   counter index i = set*8 + c,  set 0 = count_in, 1 = count_tg, 2 = inter.

// grid (BLKS, NSAMP) x 256 threads; 32 px/thread via 8 x int4 per array.
__global__ __launch_bounds__(256) void dice_count(const int* __restrict__ in,
                                                  const int* __restrict__ tg,
                                                  u32* __restrict__ partial) {
    const int n = blockIdx.y;
    const int t = threadIdx.x;
    const int4* in4 = (const int4*)(in + (size_t)n * PIX);
    const int4* tg4 = (const int4*)(tg + (size_t)n * PIX);
    const int base = blockIdx.x * 2048;  // int4 units; 32 blk * 2048 * 4 = 262144 px

    u64 pin = 0, ptg = 0, pix = 0;  // 8-bit field per class (max 32 <= 255)
#pragma unroll
    for (int i = 0; i < 8; ++i) {
        int4 a = in4[base + i * 256 + t];
        int4 b = tg4[base + i * 256 + t];
        u64 ax = 1ull << (a.x * 8), ay = 1ull << (a.y * 8);
        u64 az = 1ull << (a.z * 8), aw = 1ull << (a.w * 8);
        pin += ax + ay + az + aw;
        ptg += (1ull << (b.x * 8)) + (1ull << (b.y * 8)) +
               (1ull << (b.z * 8)) + (1ull << (b.w * 8));
        if (a.x == b.x) pix += ax;
        if (a.y == b.y) pix += ay;
        if (a.z == b.z) pix += az;
        if (a.w == b.w) pix += aw;
    }

    // Rounds 1-2 (offsets 1,2) on packed 8-bit fields: max 32*4=128 <= 255.
#pragma unroll
    for (int off = 1; off <= 2; off <<= 1) {
        pin += (u64)__shfl_xor((unsigned long long)pin, off, 64);
        ptg += (u64)__shfl_xor((unsigned long long)ptg, off, 64);
        pix += (u64)__shfl_xor((unsigned long long)pix, off, 64);
    }

    // Split 8-bit -> 16-bit fields (even classes low set, odd classes high set).
    const u64 M = 0x00FF00FF00FF00FFull;
    u64 v[6];
    v[0] = pin & M;        // count_in, classes 0,2,4,6
    v[1] = (pin >> 8) & M; // count_in, classes 1,3,5,7
    v[2] = ptg & M;
    v[3] = (ptg >> 8) & M;
    v[4] = pix & M;
    v[5] = (pix >> 8) & M;

    // Rounds 3-6 (offsets 4,8,16,32) on 16-bit fields: max 32*64=2048.
#pragma unroll
    for (int off = 4; off <= 32; off <<= 1) {
#pragma unroll
        for (int j = 0; j < 6; ++j)
            v[j] += (u64)__shfl_xor((unsigned long long)v[j], off, 64);
    }

    // Every lane now holds the full wave sum. Combine 4 waves via LDS.
    __shared__ u32 sm[4 * 24];
    const int wave = t >> 6;
    const int lane = t & 63;
    if (lane < 24) {
        const int set = lane >> 3;
        const int c   = lane & 7;
        u64 pk = v[set * 2 + (c & 1)];
        sm[wave * 24 + lane] = (u32)((pk >> (16 * (c >> 1))) & 0xFFFFull);
    }
    __syncthreads();
    if (t < 24) {
        u32 s = sm[t] + sm[24 + t] + sm[48 + t] + sm[72 + t];
        partial[((size_t)(n * BLKS + blockIdx.x)) * 24 + t] = s;
    }
}

// One block, 192 threads (3 waves). Thread t -> (n = t/24, i = t%24):
// sum 32 block-partials (fully unrolled -> 32 independent loads in flight),
// then wave 0 does the dice epilogue.
__global__ __launch_bounds__(192) void dice_final(const u32* __restrict__ partial,
                                                  const float* __restrict__ w,
                                                  float* __restrict__ out) {
    const int t = threadIdx.x;
    __shared__ u32 cnt[NSAMP * 24];

    const int n = t / 24;
    const int i = t - n * 24;
    u32 s = 0;
#pragma unroll
    for (int b = 0; b < BLKS; ++b)
        s += partial[((size_t)(n * BLKS + b)) * 24 + i];
    cnt[n * 24 + i] = s;
    __syncthreads();

    if (t < 64) {
        const int sn = t >> 3;
        const int c  = t & 7;
        float cin = (float)cnt[sn * 24 + 0 + c];
        float ctg = (float)cnt[sn * 24 + 8 + c];
        float itr = (float)cnt[sn * 24 + 16 + c];
        float dice = (2.0f * itr + SMOOTHF) / (cin + ctg + SMOOTHF);

        // Sum over samples (lanes differing in bits 3..5 share c).
        dice += __shfl_xor(dice, 8, 64);
        dice += __shfl_xor(dice, 16, 64);
        dice += __shfl_xor(dice, 32, 64);
        float mean_c = dice * 0.125f;

        if (t < 8) out[1 + t] = mean_c;

        float ws = w[c] * mean_c;
        ws += __shfl_xor(ws, 1, 64);
        ws += __shfl_xor(ws, 2, 64);
        ws += __shfl_xor(ws, 4, 64);
        if (t == 0) out[0] = ws;
    }
}

extern "C" void kernel_launch(void* const* d_in, const int* in_sizes, int n_in,
                              void* d_out, int out_size, void* d_ws, size_t ws_size,
                              hipStream_t stream) {
    const int*   in  = (const int*)d_in[0];
    const int*   tg  = (const int*)d_in[1];
    const float* w   = (const float*)d_in[2];
    float*       out = (float*)d_out;
    u32*         partial = (u32*)d_ws;  // fully overwritten every call

    dice_count<<<dim3(BLKS, NSAMP), 256, 0, stream>>>(in, tg, partial);
    dice_final<<<1, 192, 0, stream>>>(partial, w, out);
}